// Round 1
// baseline (828.206 us; speedup 1.0000x reference)
//
#include <hip/hip_runtime.h>

// LIF recurrence: T=512, B=64, N=4096.
// out[t,b,n] = heaviside(V >= Vth) with leaky integration + adaptive threshold.
// Pure HBM stream (1 GiB total traffic). One thread owns 4 consecutive channels;
// V/Vth state stays in registers across all 512 timesteps.

typedef float f32x4 __attribute__((ext_vector_type(4)));

namespace {
constexpr int kT   = 512;
constexpr int kB   = 64;
constexpr int kN   = 4096;
constexpr int kBN  = kB * kN;     // 262144 elements per timestep
constexpr int kBN4 = kBN / 4;     // 65536 float4 columns per timestep
constexpr float kDecay = 0.05f;   // DT/TAU = 1/20 (same rounding as (float)(1.0/20.0))
constexpr float kEta   = 0.1f;
constexpr float kMinTh = 0.5f;
constexpr float kMaxTh = 2.0f;
}  // namespace

__global__ __launch_bounds__(256) void lif_kernel(const f32x4* __restrict__ in,
                                                  f32x4* __restrict__ out) {
  // Match XLA: no FMA contraction — spike threshold is bit-sensitive.
#pragma clang fp contract(off)
  const int col = blockIdx.x * blockDim.x + threadIdx.x;  // [0, kBN4)

  f32x4 V  = {0.0f, 0.0f, 0.0f, 0.0f};
  f32x4 Th = {1.0f, 1.0f, 1.0f, 1.0f};

  const f32x4* ip = in + col;
  f32x4* op = out + col;

#pragma unroll 8
  for (int t = 0; t < kT; ++t) {
    const f32x4 I = __builtin_nontemporal_load(ip);
    f32x4 S;

    // Per-component LIF step, separately-rounded mul+add like the reference.
#define LIF_STEP(c)                                              \
    {                                                            \
      float d = I.c - V.c;                                       \
      float p = kDecay * d;                                      \
      float v = V.c + p;                                         \
      float s = (v >= Th.c) ? 1.0f : 0.0f;                       \
      V.c = (v >= Th.c) ? 0.0f : v;                              \
      S.c = s;                                                   \
      Th.c = fminf(fmaxf(Th.c + kEta * s, kMinTh), kMaxTh);      \
    }

    LIF_STEP(x)
    LIF_STEP(y)
    LIF_STEP(z)
    LIF_STEP(w)
#undef LIF_STEP

    __builtin_nontemporal_store(S, op);
    ip += kBN4;
    op += kBN4;
  }
}

extern "C" void kernel_launch(void* const* d_in, const int* in_sizes, int n_in,
                              void* d_out, int out_size, void* d_ws, size_t ws_size,
                              hipStream_t stream) {
  const f32x4* in = reinterpret_cast<const f32x4*>(d_in[0]);
  f32x4* out = reinterpret_cast<f32x4*>(d_out);

  const int threads = 256;
  const int blocks = kBN4 / threads;  // 65536 / 256 = 256 blocks
  lif_kernel<<<dim3(blocks), dim3(threads), 0, stream>>>(in, out);
}